// Round 5
// baseline (574.688 us; speedup 1.0000x reference)
//
#include <hip/hip_runtime.h>
#include <hip/hip_fp16.h>
#include <math.h>

#define HID 64
#define HEADS 4
#define HC (HEADS * HID)   // 256
#define IN_DIM 32
#define NEG 0.2f
#define BN_EPS 1e-5f
#define SCAN_B 256

// ---------- index dtype detection ----------
__global__ void k_detect64(const int* __restrict__ ei, int* __restrict__ flag) {
    if (blockIdx.x == 0 && threadIdx.x == 0) {
        int z = 1;
#pragma unroll
        for (int i = 1; i < 64; i += 2) z &= (ei[i] == 0);
        *flag = z;
    }
}

__device__ __forceinline__ int ld_idx(const int* __restrict__ p, int i, int f64) {
    return f64 ? p[(size_t)2 * i] : p[i];
}

__global__ void k_zero(float* __restrict__ p, int n) {
    int i = blockIdx.x * blockDim.x + threadIdx.x;
    if (i < n) p[i] = 0.f;
}
__global__ void k_zeroi(int* __restrict__ p, int n) {
    int i = blockIdx.x * blockDim.x + threadIdx.x;
    if (i < n) p[i] = 0;
}

// ---------- CSR build: count / scan / scatter ----------
__global__ void k_count(const int* __restrict__ ei, const int* __restrict__ flagp,
                        int* __restrict__ count, int E, int Etot) {
    int e = blockIdx.x * blockDim.x + threadIdx.x;
    if (e >= Etot) return;
    const int f = *flagp;
    int d = (e < E) ? ld_idx(ei, E + e, f) : e - E;
    atomicAdd(&count[d], 1);
}

__global__ void k_scan1(const int* __restrict__ in, int* __restrict__ out,
                        int* __restrict__ part, int n) {
    __shared__ int tmp[SCAN_B];
    int t = threadIdx.x;
    int i = blockIdx.x * SCAN_B + t;
    int v = (i < n) ? in[i] : 0;
    tmp[t] = v;
    __syncthreads();
    for (int off = 1; off < SCAN_B; off <<= 1) {
        int x = (t >= off) ? tmp[t - off] : 0;
        __syncthreads();
        tmp[t] += x;
        __syncthreads();
    }
    if (i < n) out[i] = tmp[t] - v;  // exclusive
    if (t == SCAN_B - 1) part[blockIdx.x] = tmp[t];
}

__global__ void k_scan2(int* __restrict__ part, int nb) {
    __shared__ int tmp[SCAN_B];
    __shared__ int carry_s;
    int t = threadIdx.x;
    if (t == 0) carry_s = 0;
    __syncthreads();
    for (int b = 0; b < nb; b += SCAN_B) {
        int carry = carry_s;
        int v = (b + t < nb) ? part[b + t] : 0;
        tmp[t] = v;
        __syncthreads();
        for (int off = 1; off < SCAN_B; off <<= 1) {
            int x = (t >= off) ? tmp[t - off] : 0;
            __syncthreads();
            tmp[t] += x;
            __syncthreads();
        }
        if (b + t < nb) part[b + t] = tmp[t] - v + carry;
        if (t == SCAN_B - 1) carry_s = carry + tmp[t];
        __syncthreads();
    }
}

__global__ void k_scan3(const int* __restrict__ scanned, const int* __restrict__ part,
                        int* __restrict__ row_ptr, int* __restrict__ cursor,
                        int n, int total) {
    int i = blockIdx.x * blockDim.x + threadIdx.x;
    if (i < n) {
        int v = scanned[i] + part[i / SCAN_B];
        row_ptr[i] = v;
        cursor[i] = v;
    }
    if (i == 0) row_ptr[n] = total;
}

__global__ void k_scatter(const int* __restrict__ ei, const int* __restrict__ flagp,
                          int* __restrict__ cursor, int* __restrict__ src_sorted,
                          int E, int Etot) {
    int e = blockIdx.x * blockDim.x + threadIdx.x;
    if (e >= Etot) return;
    const int f = *flagp;
    int s, d;
    if (e < E) { s = ld_idx(ei, e, f); d = ld_idx(ei, E + e, f); }
    else       { s = d = e - E; }
    int pos = atomicAdd(&cursor[d], 1);
    src_sorted[pos] = s;
}

// ---------- h = x @ in_W + in_b ----------
__global__ void k_input(const float* __restrict__ x, const float* __restrict__ W,
                        const float* __restrict__ b, float* __restrict__ h, int N) {
    int n = blockIdx.x;
    int c = threadIdx.x;  // 0..63
    __shared__ float xs[IN_DIM];
    if (c < IN_DIM) xs[c] = x[n * IN_DIM + c];
    __syncthreads();
    float acc = b[c];
#pragma unroll
    for (int k = 0; k < IN_DIM; ++k) acc += xs[k] * W[k * HID + c];
    h[(size_t)n * HID + c] = acc;
}

// ---------- per-layer: xt = h @ W + attention scores ----------
// 256 threads = 256 output cols; W column held in 64 VGPRs; 16 nodes/block
// staged in LDS; inner loop = float4 LDS broadcast + 4 FMA.
#define NPB 16
__global__ __launch_bounds__(256) void k_gat_xt(
        const float* __restrict__ h, const float* __restrict__ W,
        const float* __restrict__ asrc, const float* __restrict__ adst,
        __half* __restrict__ xt, float* __restrict__ ssrc,
        float* __restrict__ sdst, int N) {
    int t = threadIdx.x;           // 0..255: output column
    int head = t >> 6, lane = t & 63;
    int n0 = blockIdx.x * NPB;
    __shared__ float hs[NPB][HID];
    {   // stage 16 rows: thread t loads one float4 (row t>>4, quad t&15)
        int j = t >> 4, q = t & 15;
        int n = n0 + j;
        float4 v = (n < N) ? ((const float4*)(h + (size_t)n * HID))[q]
                           : make_float4(0.f, 0.f, 0.f, 0.f);
        ((float4*)hs[j])[q] = v;
    }
    // W column into registers (reused for all 16 nodes)
    float wreg[HID];
#pragma unroll
    for (int k = 0; k < HID; ++k) wreg[k] = W[k * HC + t];
    __syncthreads();
    float as = asrc[head * HID + lane];
    float ad = adst[head * HID + lane];
    for (int j = 0; j < NPB; ++j) {
        int n = n0 + j;
        if (n >= N) break;
        float acc = 0.f;
#pragma unroll
        for (int kk = 0; kk < HID / 4; ++kk) {
            float4 hv = ((const float4*)hs[j])[kk];
            acc += hv.x * wreg[4 * kk + 0] + hv.y * wreg[4 * kk + 1]
                 + hv.z * wreg[4 * kk + 2] + hv.w * wreg[4 * kk + 3];
        }
        xt[(size_t)n * HC + t] = __float2half(acc);
        float vs = acc * as;
        float vd = acc * ad;
#pragma unroll
        for (int m = 32; m >= 1; m >>= 1) {
            vs += __shfl_xor(vs, m, 64);
            vd += __shfl_xor(vd, m, 64);
        }
        if (lane == 0) {
            ssrc[(size_t)n * HEADS + head] = vs;
            sdst[(size_t)n * HEADS + head] = vd;
        }
    }
}

// ---------- fused aggregation + softmax + bias/BN/relu/residual ----------
// One wave per dst node; 32 lanes per edge, 2 edges per iteration.
// l32=lane&31 owns 8 channels (float4 of halves, 16 B); head = l32>>3;
// half=lane>>5 selects even/odd edge of the pair.
__global__ __launch_bounds__(256) void k_aggr(
        const int* __restrict__ row_ptr, const int* __restrict__ src_sorted,
        const float* __restrict__ ssrc, const float* __restrict__ sdst,
        const __half* __restrict__ xt,
        const float* __restrict__ gb, const float* __restrict__ bg,
        const float* __restrict__ bb, const float* __restrict__ bm,
        const float* __restrict__ bv, float* __restrict__ h, int N) {
    int wid = blockIdx.x * 4 + (threadIdx.x >> 6);
    int lane = threadIdx.x & 63;
    if (wid >= N) return;
    const int d = wid;
    const int lo = row_ptr[d], hi = row_ptr[d + 1];
    const int half = lane >> 5;
    const int l32 = lane & 31;
    const int hh = l32 >> 3;
    const float sd = sdst[d * HEADS + hh];
    float den = 0.f;
    float acc[8];
#pragma unroll
    for (int i = 0; i < 8; ++i) acc[i] = 0.f;
    for (int base = lo; base < hi; base += 64) {
        int nb = min(64, hi - base);
        int se = src_sorted[min(base + lane, hi - 1)];
        int npair = (nb + 1) >> 1;
        for (int j = 0; j < npair; ++j) {
            int sa = __shfl(se, 2 * j, 64);
            int sb = __shfl(se, 2 * j + 1, 64);
            int s = half ? sb : sa;
            bool valid = (base + 2 * j + half) < hi;
            float v = ssrc[s * HEADS + hh] + sd;
            v = v > 0.f ? v : NEG * v;
            float ex = valid ? __expf(v) : 0.f;
            den += ex;
            float4 rw = *(const float4*)(xt + (size_t)s * HC + l32 * 8);
            const __half2* hp = (const __half2*)&rw;
            float2 f0 = __half22float2(hp[0]);
            float2 f1 = __half22float2(hp[1]);
            float2 f2 = __half22float2(hp[2]);
            float2 f3 = __half22float2(hp[3]);
            acc[0] += ex * f0.x; acc[1] += ex * f0.y;
            acc[2] += ex * f1.x; acc[3] += ex * f1.y;
            acc[4] += ex * f2.x; acc[5] += ex * f2.y;
            acc[6] += ex * f3.x; acc[7] += ex * f3.y;
        }
    }
    den += __shfl_xor(den, 32, 64);        // fold the two edge-halves
    float inv = 1.f / den;                 // den > 0 (self-loop guaranteed)
#pragma unroll
    for (int i = 0; i < 8; ++i) {
        float a = acc[i] + __shfl_xor(acc[i], 32, 64);  // same head, other half
        a *= inv;                                        // per-head alpha-normalize
        a += __shfl_xor(a, 8, 64);                       // fold heads (bit0)
        a += __shfl_xor(a, 16, 64);                      // fold heads (bit1)
        acc[i] = a;
    }
    if (lane < 8) {   // lane owns channels 8*lane .. 8*lane+7
        int c0 = lane * 8;
        float* hrow = h + (size_t)d * HID;
        float4 r0 = ((const float4*)hrow)[lane * 2];
        float4 r1 = ((const float4*)hrow)[lane * 2 + 1];
        float o[8];
#pragma unroll
        for (int i = 0; i < 8; ++i) {
            int c = c0 + i;
            float v = 0.25f * acc[i] + gb[c];
            v = (v - bm[c]) * rsqrtf(bv[c] + BN_EPS) * bg[c] + bb[c];
            o[i] = fmaxf(v, 0.f);
        }
        float4 w0 = make_float4(o[0] + r0.x, o[1] + r0.y, o[2] + r0.z, o[3] + r0.w);
        float4 w1 = make_float4(o[4] + r1.x, o[5] + r1.y, o[6] + r1.z, o[7] + r1.w);
        ((float4*)hrow)[lane * 2] = w0;
        ((float4*)hrow)[lane * 2 + 1] = w1;
    }
}

// ---------- global mean pool: node-parallel partial sums ----------
#define NPBK 64
__global__ void k_pool_sum(const float* __restrict__ h, const int* __restrict__ batch,
                           const int* __restrict__ flagp, float* __restrict__ gsum, int N) {
    const int f = *flagp;
    int c = threadIdx.x;  // 0..63
    int n0 = blockIdx.x * NPBK;
    int n1 = min(n0 + NPBK, N);
    if (n0 >= N) return;
    int cur = ld_idx(batch, n0, f);
    float s = 0.f;
    for (int n = n0; n < n1; ++n) {
        int g = ld_idx(batch, n, f);
        if (g != cur) {
            atomicAdd(&gsum[cur * HID + c], s);
            s = 0.f;
            cur = g;
        }
        s += h[(size_t)n * HID + c];
    }
    atomicAdd(&gsum[cur * HID + c], s);
}

__device__ __forceinline__ int lower_bound_i(const int* __restrict__ a, int n, int v, int f) {
    int lo = 0, hi = n;
    while (lo < hi) {
        int mid = (lo + hi) >> 1;
        if (ld_idx(a, mid, f) < v) lo = mid + 1; else hi = mid;
    }
    return lo;
}

// ---------- final MLP head (mean-divide fused in) ----------
__global__ void k_mlp(const float* __restrict__ gsum, const int* __restrict__ batch,
                      const int* __restrict__ flagp, int N,
                      const float* __restrict__ W1, const float* __restrict__ b1,
                      const float* __restrict__ W2, const float* __restrict__ b2,
                      float* __restrict__ out, int OUTD) {
    int gg = blockIdx.x, c = threadIdx.x;  // 64 threads
    const int f = *flagp;
    int lo = lower_bound_i(batch, N, gg, f);
    int hi = lower_bound_i(batch, N, gg + 1, f);
    float cnt = (float)(hi - lo);
    __shared__ float gs[HID];
    __shared__ float s1[HID];
    gs[c] = gsum[gg * HID + c] / fmaxf(cnt, 1.f);
    __syncthreads();
    float acc = b1[c];
#pragma unroll
    for (int k = 0; k < HID; ++k) acc += gs[k] * W1[k * HID + c];
    s1[c] = fmaxf(acc, 0.f);
    __syncthreads();
    if (c < OUTD) {
        float o = b2[c];
#pragma unroll
        for (int k = 0; k < HID; ++k) o += s1[k] * W2[k * OUTD + c];
        out[gg * OUTD + c] = o;
    }
}

extern "C" void kernel_launch(void* const* d_in, const int* in_sizes, int n_in,
                              void* d_out, int out_size, void* d_ws, size_t ws_size,
                              hipStream_t stream) {
    const float* x       = (const float*)d_in[0];
    const int*   ei_raw  = (const int*)d_in[1];
    const int*   b_raw   = (const int*)d_in[2];
    const float* in_W    = (const float*)d_in[3];
    const float* in_b    = (const float*)d_in[4];
    const float* gat_W   = (const float*)d_in[5];
    const float* att_src = (const float*)d_in[6];
    const float* att_dst = (const float*)d_in[7];
    const float* gat_b   = (const float*)d_in[8];
    const float* bn_g    = (const float*)d_in[9];
    const float* bn_b    = (const float*)d_in[10];
    const float* bn_m    = (const float*)d_in[11];
    const float* bn_v    = (const float*)d_in[12];
    const float* fc1_W   = (const float*)d_in[13];
    const float* fc1_b   = (const float*)d_in[14];
    const float* fc2_W   = (const float*)d_in[15];
    const float* fc2_b   = (const float*)d_in[16];

    const int N = in_sizes[2];          // n_nodes
    const int E = in_sizes[1] / 2;      // edges
    const int Etot = E + N;             // + self loops
    const int OUTD = 4;
    const int G = out_size / OUTD;
    const int nb1 = (N + SCAN_B - 1) / SCAN_B;

    // ---- workspace layout (xt first for 512B alignment) ----
    __half* xt   = (__half*)d_ws;                        // N*256 halves (25.6 MB)
    float* h     = (float*)(xt + (size_t)N * HC);        // N*64
    float* ssrc  = h    + (size_t)N * HID;               // N*4
    float* sdst  = ssrc + (size_t)N * HEADS;             // N*4
    float* gsum  = sdst + (size_t)N * HEADS;             // G*64
    int*   flag    = (int*)(gsum + (size_t)G * HID);     // 1 (+pad)
    int*   count   = flag + 4;                           // N
    int*   scanned = count + N;                          // N
    int*   part    = scanned + N;                        // nb1 (+pad)
    int*   row_ptr = part + ((nb1 + 63) & ~63);          // N+1
    int*   cursor  = row_ptr + N + 1;                    // N
    int*   src_sorted = cursor + N;                      // Etot

    k_detect64<<<1, 64, 0, stream>>>(ei_raw, flag);

    // ---- CSR build (once, reused for 3 layers) ----
    k_zeroi<<<(N + 255) / 256, 256, 0, stream>>>(count, N);
    k_count<<<(Etot + 255) / 256, 256, 0, stream>>>(ei_raw, flag, count, E, Etot);
    k_scan1<<<nb1, SCAN_B, 0, stream>>>(count, scanned, part, N);
    k_scan2<<<1, SCAN_B, 0, stream>>>(part, nb1);
    k_scan3<<<(N + 255) / 256, 256, 0, stream>>>(scanned, part, row_ptr, cursor, N, Etot);
    k_scatter<<<(Etot + 255) / 256, 256, 0, stream>>>(ei_raw, flag, cursor, src_sorted, E, Etot);

    k_input<<<N, HID, 0, stream>>>(x, in_W, in_b, h, N);

    for (int l = 0; l < 3; ++l) {
        k_gat_xt<<<(N + NPB - 1) / NPB, 256, 0, stream>>>(
            h, gat_W + (size_t)l * HID * HC, att_src + (size_t)l * HEADS * HID,
            att_dst + (size_t)l * HEADS * HID, xt, ssrc, sdst, N);
        k_aggr<<<(N + 3) / 4, 256, 0, stream>>>(
            row_ptr, src_sorted, ssrc, sdst, xt,
            gat_b + (size_t)l * HID, bn_g + (size_t)l * HID, bn_b + (size_t)l * HID,
            bn_m + (size_t)l * HID, bn_v + (size_t)l * HID, h, N);
    }

    k_zero<<<(G * HID + 255) / 256, 256, 0, stream>>>(gsum, G * HID);
    k_pool_sum<<<(N + NPBK - 1) / NPBK, HID, 0, stream>>>(h, b_raw, flag, gsum, N);
    k_mlp<<<G, HID, 0, stream>>>(gsum, b_raw, flag, N, fc1_W, fc1_b, fc2_W, fc2_b,
                                 (float*)d_out, OUTD);
}